// Round 6
// baseline (7527.448 us; speedup 1.0000x reference)
//
#include <hip/hip_runtime.h>
#include <stdint.h>

#define NTOT    131072
#define NSTEP   60
#define MBLK    256
#define PLANE_H 16384          // halves per W plane
#define IMG_B   65536          // bytes per W image (hi+lo planes)
#define IMG_H   32768          // halves per W image

// LDS byte offsets
#define OFF_SLAB0 0            // 65536
#define OFF_SLAB1 65536        // 65536
#define OFF_W1C   131072       // f32x4[128] = (w1x, w1y, b1, 0) : 2048
#define OFF_B2    133120       // float[128]
#define OFF_B3    133632
#define OFF_B4    134144
#define OFF_W5    134656
#define LDS_TOTAL 135168

typedef float  f32x4  __attribute__((ext_vector_type(4)));
typedef float  f32x16 __attribute__((ext_vector_type(16)));
typedef short  bf16x8 __attribute__((ext_vector_type(8)));
union FragU { bf16x8 v; uint32_t u[4]; uint16_t h[8]; };

static __device__ __forceinline__ uint32_t rne_bits(float f) {
  uint32_t u = __float_as_uint(f);
  return u + 0x7fffu + ((u >> 16) & 1u);   // high16 = rne bf16
}
static __device__ __forceinline__ float hi_of(uint32_t tb) {
  return __uint_as_float(tb & 0xffff0000u);
}
static __device__ __forceinline__ float fsigm(float z) {
  return __builtin_amdgcn_rcpf(1.0f + __builtin_amdgcn_exp2f(z * -1.44269504089f));
}
static __device__ __forceinline__ uint32_t packbits(uint32_t ta, uint32_t tb) {
  return __builtin_amdgcn_perm(tb, ta, 0x07060302u);   // bf16(a) | bf16(b)<<16
}

// ---- prep: 6 fragment-order (32x32x16 A-layout) split-bf16 W images ----
// img 0..2: forward A = W^T of w2,w3,w4 (m=out, k=in)
// img 3..5: backward A = W natural of w4,w3,w2 (m=in, k=out)
extern "C" __global__ void ebm_prep_kernel(const float* __restrict__ w2,
                                           const float* __restrict__ w3,
                                           const float* __restrict__ w4,
                                           uint16_t* __restrict__ ws) {
  int img = blockIdx.x;
  bool bwd = img >= 3;
  int li = bwd ? 5 - img : img;
  const float* w = (li == 0) ? w2 : (li == 1) ? w3 : w4;
  uint16_t* hiP = ws + (size_t)img * IMG_H;
  uint16_t* loP = hiP + PLANE_H;
  for (int e = threadIdx.x; e < 16384; e += blockDim.x) {
    int i = e >> 7, o = e & 127;            // w[i][o]
    int m = bwd ? i : o;
    int k = bwd ? o : i;
    int slot = ((m >> 5) * 8 + (k >> 4)) * 64 + (m & 31) + 32 * ((k >> 3) & 1);
    int off = slot * 8 + (k & 7);
    float v = w[e];
    uint32_t tb = rne_bits(v);
    float lo = v - hi_of(tb);
    hiP[off] = (uint16_t)(tb >> 16);
    loP[off] = (uint16_t)(rne_bits(lo) >> 16);
  }
}

extern "C" __global__ void __launch_bounds__(512, 2)
ebm_mcmc_kernel(const float* __restrict__ x0, const float* __restrict__ w1,
                const float* __restrict__ b1, const float* __restrict__ b2,
                const float* __restrict__ b3, const float* __restrict__ b4,
                const float* __restrict__ w5, const float* __restrict__ noise,
                const uint16_t* __restrict__ wsW, float* __restrict__ out)
{
  extern __shared__ char smem[];
  f32x4* W1C = (f32x4*)(smem + OFF_W1C);
  float* B2s = (float*)(smem + OFF_B2);
  float* B3s = (float*)(smem + OFF_B3);
  float* B4s = (float*)(smem + OFF_B4);
  float* W5s = (float*)(smem + OFF_W5);

  const int t    = threadIdx.x;
  const int blk  = blockIdx.x;
  const int lane = t & 63;
  const int wave = t >> 6;
  const int n    = lane & 31;
  const int h    = lane >> 5;                 // lane half
  const int s    = blk * MBLK + wave * 32 + n;  // this lane's sample (all layers)

  auto stage_w = [&](int img, int buf) {
    const char* src = (const char*)wsW + (size_t)img * IMG_B;
    char* dst = smem + (buf ? OFF_SLAB1 : OFF_SLAB0);
    typedef const __attribute__((address_space(1))) unsigned int GU32;
    typedef __attribute__((address_space(3))) unsigned int LU32;
#pragma unroll
    for (int it = 0; it < 8; ++it) {
      int off = (it * 512 + t) * 16;
      __builtin_amdgcn_global_load_lds((GU32*)(src + off), (LU32*)(dst + off), 16, 0, 0);
    }
  };

  if (t < 128) {
    f32x4 v; v.x = w1[t]; v.y = w1[128 + t]; v.z = b1[t]; v.w = 0.0f;
    W1C[t] = v;
    B2s[t] = b2[t]; B3s[t] = b3[t]; B4s[t] = b4[t]; W5s[t] = w5[t];
  }
  float2 xv = *(const float2*)(x0 + (size_t)s * 2);
  float xa = xv.x, xb = xv.y;
  stage_w(0, 0);
  __syncthreads();

  f32x16 acc[4];
  FragU  Bh[8], Bl[8];        // current B operand (activations), register-resident
  FragU  Bth[8], Btl[8];      // temp h1 operand for the z2' recompute gemm
  float  D3[64], D2[64];      // silu' slices (C-space), short-lived

  auto mfma = [&](FragU a, FragU b, f32x16 c) {
    return __builtin_amdgcn_mfma_f32_32x32x16_bf16(a.v, b.v, c, 0, 0, 0);
  };

  auto gemm = [&](int rb, const FragU* Xh, const FragU* Xl) {
    const uint16_t* sp = (const uint16_t*)(smem + (rb ? OFF_SLAB1 : OFF_SLAB0));
#pragma unroll
    for (int rt = 0; rt < 4; ++rt) acc[rt] = (f32x16)0.0f;
#pragma unroll
    for (int g = 0; g < 8; ++g) {
#pragma unroll
      for (int rt = 0; rt < 4; ++rt) {
        const uint16_t* ap = sp + ((rt * 8 + g) * 64 + lane) * 8;
        FragU Ah, Al;
        Ah.v = *(const bf16x8*)ap;
        Al.v = *(const bf16x8*)(ap + PLANE_H);
        acc[rt] = mfma(Ah, Xh[g], acc[rt]);
        acc[rt] = mfma(Ah, Xl[g], acc[rt]);
        acc[rt] = mfma(Al, Xh[g], acc[rt]);
      }
    }
  };

  // split-pack 8 fp32 slot values into hi/lo bf16 frags
  auto pack8 = [&](FragU& H, FragU& L, const float* sv) {
    uint32_t hb[8];
#pragma unroll
    for (int j = 0; j < 8; ++j) hb[j] = rne_bits(sv[j]);
#pragma unroll
    for (int i = 0; i < 4; ++i) H.u[i] = packbits(hb[2 * i], hb[2 * i + 1]);
    float lo[8];
#pragma unroll
    for (int j = 0; j < 8; ++j) lo[j] = sv[j] - hi_of(hb[j]);
#pragma unroll
    for (int i = 0; i < 4; ++i)
      L.u[i] = packbits(rne_bits(lo[2 * i]), rne_bits(lo[2 * i + 1]));
  };

  // C-tile (rt) -> B-frag groups 2rt, 2rt+1 via half-exchange (derivation in notes)
  auto xform_tile = [&](int rt, const float* pv) {
#pragma unroll
    for (int gg = 0; gg < 2; ++gg) {
      int g = 2 * rt + gg, base = 8 * gg;
      float sv[8];
#pragma unroll
      for (int j = 0; j < 4; ++j) {
        float qA = pv[base + j], qB = pv[base + 4 + j];
        float snd = h ? qA : qB;
        float rcv = __shfl_xor(snd, 32, 64);
        sv[j]     = h ? rcv : qA;
        sv[4 + j] = h ? qB : rcv;
      }
      pack8(Bh[g], Bl[g], sv);
    }
  };

  auto ep_fwd2 = [&]() {               // h2 = silu(z2+b2), no D save
#pragma unroll
    for (int rt = 0; rt < 4; ++rt) {
      float pv[16];
#pragma unroll
      for (int a = 0; a < 4; ++a) {
        f32x4 bv = *(const f32x4*)(B2s + 32 * rt + 8 * a + 4 * h);
#pragma unroll
        for (int b = 0; b < 4; ++b) {
          int r = 4 * a + b;
          float z = acc[rt][r] + bv[b];
          float sg = fsigm(z);
          pv[r] = z * sg;
        }
      }
      xform_tile(rt, pv);
    }
  };

  auto ep_fwd3 = [&]() {               // h3 + D3
#pragma unroll
    for (int rt = 0; rt < 4; ++rt) {
      float pv[16];
#pragma unroll
      for (int a = 0; a < 4; ++a) {
        f32x4 bv = *(const f32x4*)(B3s + 32 * rt + 8 * a + 4 * h);
#pragma unroll
        for (int b = 0; b < 4; ++b) {
          int r = 4 * a + b;
          float z = acc[rt][r] + bv[b];
          float sg = fsigm(z);
          float hh = z * sg;
          D3[rt * 16 + r] = sg * (1.0f + z - hh);
          pv[r] = hh;
        }
      }
      xform_tile(rt, pv);
    }
  };

  auto ep_v4 = [&]() {                 // v4 = w5 * silu'(z4+b4)
#pragma unroll
    for (int rt = 0; rt < 4; ++rt) {
      float pv[16];
#pragma unroll
      for (int a = 0; a < 4; ++a) {
        f32x4 bv = *(const f32x4*)(B4s + 32 * rt + 8 * a + 4 * h);
        f32x4 wv = *(const f32x4*)(W5s + 32 * rt + 8 * a + 4 * h);
#pragma unroll
        for (int b = 0; b < 4; ++b) {
          int r = 4 * a + b;
          float z = acc[rt][r] + bv[b];
          float sg = fsigm(z);
          pv[r] = wv[b] * (sg * (1.0f + z - z * sg));
        }
      }
      xform_tile(rt, pv);
    }
  };

  auto ep_u3 = [&]() {                 // v3 = u3 .* D3
#pragma unroll
    for (int rt = 0; rt < 4; ++rt) {
      float pv[16];
#pragma unroll
      for (int r = 0; r < 16; ++r) pv[r] = acc[rt][r] * D3[rt * 16 + r];
      xform_tile(rt, pv);
    }
  };

  auto ep_d2 = [&]() {                 // D2 = silu'(z2'+b2), Bcur untouched
#pragma unroll
    for (int rt = 0; rt < 4; ++rt)
#pragma unroll
      for (int a = 0; a < 4; ++a) {
        f32x4 bv = *(const f32x4*)(B2s + 32 * rt + 8 * a + 4 * h);
#pragma unroll
        for (int b = 0; b < 4; ++b) {
          int r = 4 * a + b;
          float z = acc[rt][r] + bv[b];
          float sg = fsigm(z);
          D2[rt * 16 + r] = sg * (1.0f + z - z * sg);
        }
      }
  };

  auto ep_u2 = [&]() {                 // v2 = u2 .* D2
#pragma unroll
    for (int rt = 0; rt < 4; ++rt) {
      float pv[16];
#pragma unroll
      for (int r = 0; r < 16; ++r) pv[r] = acc[rt][r] * D2[rt * 16 + r];
      xform_tile(rt, pv);
    }
  };

  // h1 built directly in B-frag space (k = 16g+8h+j), from current x
  auto l1_build = [&](FragU* Th, FragU* Tl) {
#pragma unroll
    for (int g = 0; g < 8; ++g) {
      float sv[8];
#pragma unroll
      for (int j = 0; j < 8; ++j) {
        int k = 16 * g + 8 * h + j;
        f32x4 wv = W1C[k];
        float z = fmaf(xa, wv.x, fmaf(xb, wv.y, wv.z));
        float sg = fsigm(z);
        sv[j] = z * sg;
      }
      pack8(Th[g], Tl[g], sv);
    }
  };

  // u1 (acc) -> v1 -> g -> x update (all in regs; halves duplicate x)
  auto ep_bwd1_update = [&](int step, float2 nzv) {
    float gx = 0.f, gy = 0.f;
#pragma unroll
    for (int g = 0; g < 8; ++g) {
      int rt = g >> 1, base = 8 * (g & 1);
      float sv[8];
#pragma unroll
      for (int j = 0; j < 4; ++j) {
        float qA = acc[rt][base + j], qB = acc[rt][base + 4 + j];
        float snd = h ? qA : qB;
        float rcv = __shfl_xor(snd, 32, 64);
        sv[j]     = h ? rcv : qA;
        sv[4 + j] = h ? qB : rcv;
      }
#pragma unroll
      for (int j = 0; j < 8; ++j) {
        int k = 16 * g + 8 * h + j;
        f32x4 wv = W1C[k];
        float z = fmaf(xa, wv.x, fmaf(xb, wv.y, wv.z));
        float sg = fsigm(z);
        float hh = z * sg;
        float d1 = sg * (1.0f + z - hh);
        float v1 = sv[j] * d1;
        gx = fmaf(v1, wv.x, gx);
        gy = fmaf(v1, wv.y, gy);
      }
    }
    gx += __shfl_xor(gx, 32, 64);
    gy += __shfl_xor(gy, 32, 64);
    gx = fminf(fmaxf(gx, -0.03f), 0.03f);
    gy = fminf(fmaxf(gy, -0.03f), 0.03f);
    float epsv = 10.0f * (1.0f - (float)step / 60.0f);
    float sc = sqrtf(2.0f * epsv) * 0.005f;
    xa = fminf(fmaxf(xa + sc * nzv.x + epsv * gx, -2.43f), 3.05f);
    xb = fminf(fmaxf(xb + sc * nzv.y + epsv * gy, -2.43f), 3.05f);
    if (step == NSTEP - 1 && h == 0)
      *(float2*)(out + (size_t)s * 2) = make_float2(xa, xb);
  };

  l1_build(Bh, Bl);            // initial h1
  int rb = 0;

#pragma unroll 1
  for (int step = 0; step < NSTEP; ++step) {
    float2 nzv = *(const float2*)(noise + ((size_t)step * NTOT + s) * 2);
    // [1] z2 = W2f . h1
    stage_w(1, rb ^ 1); gemm(rb, Bh, Bl); __syncthreads(); rb ^= 1;
    ep_fwd2();                                   // B := h2
    // [2] z3 = W3f . h2
    stage_w(2, rb ^ 1); gemm(rb, Bh, Bl); __syncthreads(); rb ^= 1;
    ep_fwd3();                                   // D3, B := h3
    // [3] z4 = W4f . h3
    stage_w(3, rb ^ 1); gemm(rb, Bh, Bl); __syncthreads(); rb ^= 1;
    ep_v4();                                     // B := v4
    // [4] u3 = W4b . v4
    stage_w(0, rb ^ 1); gemm(rb, Bh, Bl); __syncthreads(); rb ^= 1;
    ep_u3();                                     // B := v3 (D3 dies)
    // [5] z2' = W2f . h1  (D2 regen; Bcur preserved)
    l1_build(Bth, Btl);
    stage_w(4, rb ^ 1); gemm(rb, Bth, Btl); __syncthreads(); rb ^= 1;
    ep_d2();
    // [6] u2 = W3b . v3
    stage_w(5, rb ^ 1); gemm(rb, Bh, Bl); __syncthreads(); rb ^= 1;
    ep_u2();                                     // B := v2 (D2 dies)
    // [7] u1 = W2b . v2
    stage_w(0, rb ^ 1); gemm(rb, Bh, Bl); __syncthreads(); rb ^= 1;
    ep_bwd1_update(step, nzv);                   // g, x update
    l1_build(Bh, Bl);                            // B := h1 (new x)
  }
}

extern "C" void kernel_launch(void* const* d_in, const int* in_sizes, int n_in,
                              void* d_out, int out_size, void* d_ws, size_t ws_size,
                              hipStream_t stream) {
  // inputs: x0,w1,b1,w2,b2,w3,b3,w4,b4,w5,b5,noise
  (void)in_sizes; (void)n_in; (void)out_size; (void)ws_size;
  hipFuncSetAttribute((const void*)ebm_mcmc_kernel,
                      hipFuncAttributeMaxDynamicSharedMemorySize, LDS_TOTAL);
  ebm_prep_kernel<<<6, 256, 0, stream>>>(
      (const float*)d_in[3], (const float*)d_in[5], (const float*)d_in[7],
      (uint16_t*)d_ws);
  ebm_mcmc_kernel<<<NTOT / MBLK, 512, LDS_TOTAL, stream>>>(
      (const float*)d_in[0], (const float*)d_in[1], (const float*)d_in[2],
      (const float*)d_in[4], (const float*)d_in[6], (const float*)d_in[8],
      (const float*)d_in[9], (const float*)d_in[11], (const uint16_t*)d_ws,
      (float*)d_out);
}

// Round 7
// 7492.892 us; speedup vs baseline: 1.0046x; 1.0046x over previous
//
#include <hip/hip_runtime.h>
#include <stdint.h>

#define NTOT    131072
#define NSTEP   60
#define MBLK    256
#define PLANE_H 16384          // halves per W plane
#define IMG_B   65536          // bytes per W image (hi+lo planes)
#define IMG_H   32768          // halves per W image

// LDS byte offsets
#define OFF_SLAB0 0            // 65536
#define OFF_SLAB1 65536        // 65536
#define OFF_W1C   131072       // f32x4[128] = (w1x, w1y, b1, 0) : 2048
#define OFF_B2    133120       // float[128]
#define OFF_B3    133632
#define OFF_B4    134144
#define OFF_W5    134656
#define LDS_TOTAL 135168

typedef float  f32x4  __attribute__((ext_vector_type(4)));
typedef float  f32x16 __attribute__((ext_vector_type(16)));
typedef short  bf16x8 __attribute__((ext_vector_type(8)));
union FragU { bf16x8 v; uint32_t u[4]; uint16_t h[8]; };

static __device__ __forceinline__ uint32_t rne_bits(float f) {
  uint32_t u = __float_as_uint(f);
  return u + 0x7fffu + ((u >> 16) & 1u);   // high16 = rne bf16
}
static __device__ __forceinline__ float hi_of(uint32_t tb) {
  return __uint_as_float(tb & 0xffff0000u);
}
static __device__ __forceinline__ float fsigm(float z) {
  return __builtin_amdgcn_rcpf(1.0f + __builtin_amdgcn_exp2f(z * -1.44269504089f));
}
static __device__ __forceinline__ uint32_t packbits(uint32_t ta, uint32_t tb) {
  return __builtin_amdgcn_perm(tb, ta, 0x07060302u);   // bf16(a) | bf16(b)<<16
}

// ---- prep: 6 fragment-order (32x32x16 A-layout) split-bf16 W images ----
// img 0..2: forward A = W^T of w2,w3,w4 (m=out, k=in)
// img 3..5: backward A = W natural of w4,w3,w2 (m=in, k=out)
extern "C" __global__ void ebm_prep_kernel(const float* __restrict__ w2,
                                           const float* __restrict__ w3,
                                           const float* __restrict__ w4,
                                           uint16_t* __restrict__ ws) {
  int img = blockIdx.x;
  bool bwd = img >= 3;
  int li = bwd ? 5 - img : img;
  const float* w = (li == 0) ? w2 : (li == 1) ? w3 : w4;
  uint16_t* hiP = ws + (size_t)img * IMG_H;
  uint16_t* loP = hiP + PLANE_H;
  for (int e = threadIdx.x; e < 16384; e += blockDim.x) {
    int i = e >> 7, o = e & 127;            // w[i][o]
    int m = bwd ? i : o;
    int k = bwd ? o : i;
    int slot = ((m >> 5) * 8 + (k >> 4)) * 64 + (m & 31) + 32 * ((k >> 3) & 1);
    int off = slot * 8 + (k & 7);
    float v = w[e];
    uint32_t tb = rne_bits(v);
    float lo = v - hi_of(tb);
    hiP[off] = (uint16_t)(tb >> 16);
    loP[off] = (uint16_t)(rne_bits(lo) >> 16);
  }
}

extern "C" __global__ void __launch_bounds__(512, 1)
ebm_mcmc_kernel(const float* __restrict__ x0, const float* __restrict__ w1,
                const float* __restrict__ b1, const float* __restrict__ b2,
                const float* __restrict__ b3, const float* __restrict__ b4,
                const float* __restrict__ w5, const float* __restrict__ noise,
                const uint16_t* __restrict__ wsW, float* __restrict__ out)
{
  extern __shared__ char smem[];
  f32x4* W1C = (f32x4*)(smem + OFF_W1C);
  float* B2s = (float*)(smem + OFF_B2);
  float* B3s = (float*)(smem + OFF_B3);
  float* B4s = (float*)(smem + OFF_B4);
  float* W5s = (float*)(smem + OFF_W5);

  const int t    = threadIdx.x;
  const int blk  = blockIdx.x;
  const int lane = t & 63;
  const int wave = t >> 6;
  const int n    = lane & 31;
  const int h    = lane >> 5;                   // lane half
  const int s    = blk * MBLK + wave * 32 + n;  // this lane's sample (all layers)

  auto stage_w = [&](int img, int buf) {
    const char* src = (const char*)wsW + (size_t)img * IMG_B;
    char* dst = smem + (buf ? OFF_SLAB1 : OFF_SLAB0);
    typedef const __attribute__((address_space(1))) unsigned int GU32;
    typedef __attribute__((address_space(3))) unsigned int LU32;
#pragma unroll
    for (int it = 0; it < 8; ++it) {
      int off = (it * 512 + t) * 16;
      __builtin_amdgcn_global_load_lds((GU32*)(src + off), (LU32*)(dst + off), 16, 0, 0);
    }
  };

  if (t < 128) {
    f32x4 v; v.x = w1[t]; v.y = w1[128 + t]; v.z = b1[t]; v.w = 0.0f;
    W1C[t] = v;
    B2s[t] = b2[t]; B3s[t] = b3[t]; B4s[t] = b4[t]; W5s[t] = w5[t];
  }
  float2 xv = *(const float2*)(x0 + (size_t)s * 2);
  float xa = xv.x, xb = xv.y;
  stage_w(0, 0);
  __syncthreads();

  f32x16 acc[4];
  FragU  Bh[8], Bl[8];        // activations operand, register-resident
  float  D3[64], D2[64];      // silu' fp32 (C-space), short-lived

  auto mfma = [&](FragU a, FragU b, f32x16 c) {
    return __builtin_amdgcn_mfma_f32_32x32x16_bf16(a.v, b.v, c, 0, 0, 0);
  };

  // split-pack 8 fp32 slot values into hi/lo bf16 frags
  auto pack8 = [&](FragU& H, FragU& L, const float* sv) {
    uint32_t hb[8];
#pragma unroll
    for (int j = 0; j < 8; ++j) hb[j] = rne_bits(sv[j]);
#pragma unroll
    for (int i = 0; i < 4; ++i) H.u[i] = packbits(hb[2 * i], hb[2 * i + 1]);
    float lo[8];
#pragma unroll
    for (int j = 0; j < 8; ++j) lo[j] = sv[j] - hi_of(hb[j]);
#pragma unroll
    for (int i = 0; i < 4; ++i)
      L.u[i] = packbits(rne_bits(lo[2 * i]), rne_bits(lo[2 * i + 1]));
  };

  // GEMM with register-resident B operand
  auto gemm = [&](int rb) {
    const uint16_t* sp = (const uint16_t*)(smem + (rb ? OFF_SLAB1 : OFF_SLAB0));
#pragma unroll
    for (int rt = 0; rt < 4; ++rt) acc[rt] = (f32x16)0.0f;
#pragma unroll
    for (int g = 0; g < 8; ++g) {
#pragma unroll
      for (int rt = 0; rt < 4; ++rt) {
        const uint16_t* ap = sp + ((rt * 8 + g) * 64 + lane) * 8;
        FragU Ah, Al;
        Ah.v = *(const bf16x8*)ap;
        Al.v = *(const bf16x8*)(ap + PLANE_H);
        acc[rt] = mfma(Ah, Bh[g], acc[rt]);
        acc[rt] = mfma(Ah, Bl[g], acc[rt]);
        acc[rt] = mfma(Al, Bh[g], acc[rt]);
      }
    }
  };

  // GEMM whose B operand (h1 = silu(x@w1+b1)) is built inline per k-group
  // from current x — only 1 group (8 regs) live at a time.
  auto gemm_h1 = [&](int rb) {
    const uint16_t* sp = (const uint16_t*)(smem + (rb ? OFF_SLAB1 : OFF_SLAB0));
#pragma unroll
    for (int rt = 0; rt < 4; ++rt) acc[rt] = (f32x16)0.0f;
#pragma unroll
    for (int g = 0; g < 8; ++g) {
      float sv[8];
#pragma unroll
      for (int j = 0; j < 8; ++j) {
        int k = 16 * g + 8 * h + j;
        f32x4 wv = W1C[k];
        float z = fmaf(xa, wv.x, fmaf(xb, wv.y, wv.z));
        float sg = fsigm(z);
        sv[j] = z * sg;
      }
      FragU Th, Tl;
      pack8(Th, Tl, sv);
#pragma unroll
      for (int rt = 0; rt < 4; ++rt) {
        const uint16_t* ap = sp + ((rt * 8 + g) * 64 + lane) * 8;
        FragU Ah, Al;
        Ah.v = *(const bf16x8*)ap;
        Al.v = *(const bf16x8*)(ap + PLANE_H);
        acc[rt] = mfma(Ah, Th, acc[rt]);
        acc[rt] = mfma(Ah, Tl, acc[rt]);
        acc[rt] = mfma(Al, Th, acc[rt]);
      }
    }
  };

  // C-tile (rt) -> B-frag groups 2rt, 2rt+1 via half-exchange
  auto xform_tile = [&](int rt, const float* pv) {
#pragma unroll
    for (int gg = 0; gg < 2; ++gg) {
      int g = 2 * rt + gg, base = 8 * gg;
      float sv[8];
#pragma unroll
      for (int j = 0; j < 4; ++j) {
        float qA = pv[base + j], qB = pv[base + 4 + j];
        float snd = h ? qA : qB;
        float rcv = __shfl_xor(snd, 32, 64);
        sv[j]     = h ? rcv : qA;
        sv[4 + j] = h ? qB : rcv;
      }
      pack8(Bh[g], Bl[g], sv);
    }
  };

  auto ep_fwd2 = [&]() {               // h2 = silu(z2+b2), no D save
#pragma unroll
    for (int rt = 0; rt < 4; ++rt) {
      float pv[16];
#pragma unroll
      for (int a = 0; a < 4; ++a) {
        f32x4 bv = *(const f32x4*)(B2s + 32 * rt + 8 * a + 4 * h);
#pragma unroll
        for (int b = 0; b < 4; ++b) {
          int r = 4 * a + b;
          float z = acc[rt][r] + bv[b];
          float sg = fsigm(z);
          pv[r] = z * sg;
        }
      }
      xform_tile(rt, pv);
    }
  };

  auto ep_fwd3 = [&]() {               // h3 + D3
#pragma unroll
    for (int rt = 0; rt < 4; ++rt) {
      float pv[16];
#pragma unroll
      for (int a = 0; a < 4; ++a) {
        f32x4 bv = *(const f32x4*)(B3s + 32 * rt + 8 * a + 4 * h);
#pragma unroll
        for (int b = 0; b < 4; ++b) {
          int r = 4 * a + b;
          float z = acc[rt][r] + bv[b];
          float sg = fsigm(z);
          float hh = z * sg;
          D3[rt * 16 + r] = sg * (1.0f + z - hh);
          pv[r] = hh;
        }
      }
      xform_tile(rt, pv);
    }
  };

  auto ep_v4 = [&]() {                 // v4 = w5 * silu'(z4+b4)
#pragma unroll
    for (int rt = 0; rt < 4; ++rt) {
      float pv[16];
#pragma unroll
      for (int a = 0; a < 4; ++a) {
        f32x4 bv = *(const f32x4*)(B4s + 32 * rt + 8 * a + 4 * h);
        f32x4 wv = *(const f32x4*)(W5s + 32 * rt + 8 * a + 4 * h);
#pragma unroll
        for (int b = 0; b < 4; ++b) {
          int r = 4 * a + b;
          float z = acc[rt][r] + bv[b];
          float sg = fsigm(z);
          pv[r] = wv[b] * (sg * (1.0f + z - z * sg));
        }
      }
      xform_tile(rt, pv);
    }
  };

  auto ep_u3 = [&]() {                 // v3 = u3 .* D3 (D3 dies)
#pragma unroll
    for (int rt = 0; rt < 4; ++rt) {
      float pv[16];
#pragma unroll
      for (int r = 0; r < 16; ++r) pv[r] = acc[rt][r] * D3[rt * 16 + r];
      xform_tile(rt, pv);
    }
  };

  auto ep_d2 = [&]() {                 // D2 = silu'(z2'+b2); B (v3) untouched
#pragma unroll
    for (int rt = 0; rt < 4; ++rt)
#pragma unroll
      for (int a = 0; a < 4; ++a) {
        f32x4 bv = *(const f32x4*)(B2s + 32 * rt + 8 * a + 4 * h);
#pragma unroll
        for (int b = 0; b < 4; ++b) {
          int r = 4 * a + b;
          float z = acc[rt][r] + bv[b];
          float sg = fsigm(z);
          D2[rt * 16 + r] = sg * (1.0f + z - z * sg);
        }
      }
  };

  auto ep_u2 = [&]() {                 // v2 = u2 .* D2 (D2 dies)
#pragma unroll
    for (int rt = 0; rt < 4; ++rt) {
      float pv[16];
#pragma unroll
      for (int r = 0; r < 16; ++r) pv[r] = acc[rt][r] * D2[rt * 16 + r];
      xform_tile(rt, pv);
    }
  };

  // u1 (acc) -> v1 -> g -> x update (all in regs; halves duplicate x)
  auto ep_bwd1_update = [&](int step, float2 nzv) {
    float gx = 0.f, gy = 0.f;
#pragma unroll
    for (int g = 0; g < 8; ++g) {
      int rt = g >> 1, base = 8 * (g & 1);
      float sv[8];
#pragma unroll
      for (int j = 0; j < 4; ++j) {
        float qA = acc[rt][base + j], qB = acc[rt][base + 4 + j];
        float snd = h ? qA : qB;
        float rcv = __shfl_xor(snd, 32, 64);
        sv[j]     = h ? rcv : qA;
        sv[4 + j] = h ? qB : rcv;
      }
#pragma unroll
      for (int j = 0; j < 8; ++j) {
        int k = 16 * g + 8 * h + j;
        f32x4 wv = W1C[k];
        float z = fmaf(xa, wv.x, fmaf(xb, wv.y, wv.z));
        float sg = fsigm(z);
        float hh = z * sg;
        float d1 = sg * (1.0f + z - hh);
        float v1 = sv[j] * d1;
        gx = fmaf(v1, wv.x, gx);
        gy = fmaf(v1, wv.y, gy);
      }
    }
    gx += __shfl_xor(gx, 32, 64);
    gy += __shfl_xor(gy, 32, 64);
    gx = fminf(fmaxf(gx, -0.03f), 0.03f);
    gy = fminf(fmaxf(gy, -0.03f), 0.03f);
    float epsv = 10.0f * (1.0f - (float)step / 60.0f);
    float sc = sqrtf(2.0f * epsv) * 0.005f;
    xa = fminf(fmaxf(xa + sc * nzv.x + epsv * gx, -2.43f), 3.05f);
    xb = fminf(fmaxf(xb + sc * nzv.y + epsv * gy, -2.43f), 3.05f);
    if (step == NSTEP - 1 && h == 0)
      *(float2*)(out + (size_t)s * 2) = make_float2(xa, xb);
  };

  int rb = 0;

#pragma unroll 1
  for (int step = 0; step < NSTEP; ++step) {
    float2 nzv = *(const float2*)(noise + ((size_t)step * NTOT + s) * 2);
    // [1] z2 = W2f . h1(x)          (h1 built inline)
    stage_w(1, rb ^ 1); gemm_h1(rb); __syncthreads(); rb ^= 1;
    ep_fwd2();                                   // B := h2
    // [2] z3 = W3f . h2
    stage_w(2, rb ^ 1); gemm(rb);    __syncthreads(); rb ^= 1;
    ep_fwd3();                                   // D3, B := h3
    // [3] z4 = W4f . h3
    stage_w(3, rb ^ 1); gemm(rb);    __syncthreads(); rb ^= 1;
    ep_v4();                                     // B := v4
    // [4] u3 = W4b . v4
    stage_w(0, rb ^ 1); gemm(rb);    __syncthreads(); rb ^= 1;
    ep_u3();                                     // B := v3 (D3 dies)
    // [5] z2' = W2f . h1(x)         (h1 built inline; B preserved)
    stage_w(4, rb ^ 1); gemm_h1(rb); __syncthreads(); rb ^= 1;
    ep_d2();                                     // D2
    // [6] u2 = W3b . v3
    stage_w(5, rb ^ 1); gemm(rb);    __syncthreads(); rb ^= 1;
    ep_u2();                                     // B := v2 (D2 dies)
    // [7] u1 = W2b . v2
    stage_w(0, rb ^ 1); gemm(rb);    __syncthreads(); rb ^= 1;
    ep_bwd1_update(step, nzv);                   // g, x update
  }
}

extern "C" void kernel_launch(void* const* d_in, const int* in_sizes, int n_in,
                              void* d_out, int out_size, void* d_ws, size_t ws_size,
                              hipStream_t stream) {
  // inputs: x0,w1,b1,w2,b2,w3,b3,w4,b4,w5,b5,noise
  (void)in_sizes; (void)n_in; (void)out_size; (void)ws_size;
  hipFuncSetAttribute((const void*)ebm_mcmc_kernel,
                      hipFuncAttributeMaxDynamicSharedMemorySize, LDS_TOTAL);
  ebm_prep_kernel<<<6, 256, 0, stream>>>(
      (const float*)d_in[3], (const float*)d_in[5], (const float*)d_in[7],
      (uint16_t*)d_ws);
  ebm_mcmc_kernel<<<NTOT / MBLK, 512, LDS_TOTAL, stream>>>(
      (const float*)d_in[0], (const float*)d_in[1], (const float*)d_in[2],
      (const float*)d_in[4], (const float*)d_in[6], (const float*)d_in[8],
      (const float*)d_in[9], (const float*)d_in[11], (const uint16_t*)d_ws,
      (float*)d_out);
}